// Round 13
// baseline (252.442 us; speedup 1.0000x reference)
//
#include <hip/hip_runtime.h>
#include <math.h>

#define L_SEQ 2048
#define BATCH 2
#define EMB 1024
#define NH 16
#define HDIM 64
#define F3 3072
#define NROWS 4096   // L_SEQ * BATCH
#define WK 1024      // K of both weight matrices

typedef __bf16 bf16_t;
typedef short s16x8 __attribute__((ext_vector_type(8)));
typedef float f32x4 __attribute__((ext_vector_type(4)));

#define MFMA16(a, b, c) __builtin_amdgcn_mfma_f32_16x16x32_bf16(a, b, c, 0, 0, 0)

// ws slots (uint bits of fp32 absmax):
// [0]=absmax(in_w) [1]=absmax(out_w) [2]=absmax(X) [3]=max|int| of Xq Q-region
// [4]=absmax(heads) [5]=absmax(y)

__device__ __forceinline__ float u2f(unsigned u) { return __uint_as_float(u); }

__device__ __forceinline__ float max3f(float a, float b, float c) {
  return fmaxf(fmaxf(a, b), c);   // clang fuses to v_max3_f32; fmax exactly associative
}

__device__ __forceinline__ void gload16(const bf16_t* g, bf16_t* lds) {
  __builtin_amdgcn_global_load_lds((const __attribute__((address_space(1))) void*)g,
                                   (__attribute__((address_space(3))) void*)lds, 16, 0, 0);
}

__device__ __forceinline__ void blockmax_commit(float m, unsigned* slot) {
  #pragma unroll
  for (int o = 1; o < 64; o <<= 1) m = fmaxf(m, __shfl_xor(m, o));
  __shared__ float sm_[4];
  if ((threadIdx.x & 63) == 0) sm_[threadIdx.x >> 6] = m;
  __syncthreads();
  if (threadIdx.x == 0) {
    float mm = fmaxf(fmaxf(sm_[0], sm_[1]), fmaxf(sm_[2], sm_[3]));
    atomicMax(slot, __float_as_uint(mm));
  }
}

// absmax of in_w -> slot0 and out_w -> slot1, one launch
__global__ __launch_bounds__(256) void wabsmax_k(const float* __restrict__ wi,
                                                 const float* __restrict__ wo,
                                                 unsigned* __restrict__ slots) {
  float m0 = 0.0f, m1 = 0.0f;
  const int n0 = F3 * EMB / 4, n1 = EMB * EMB / 4;
  for (int i = blockIdx.x * blockDim.x + threadIdx.x; i < n0; i += gridDim.x * blockDim.x) {
    float4 v = ((const float4*)wi)[i];
    m0 = fmaxf(m0, fmaxf(fmaxf(fabsf(v.x), fabsf(v.y)), fmaxf(fabsf(v.z), fabsf(v.w))));
  }
  for (int i = blockIdx.x * blockDim.x + threadIdx.x; i < n1; i += gridDim.x * blockDim.x) {
    float4 v = ((const float4*)wo)[i];
    m1 = fmaxf(m1, fmaxf(fmaxf(fabsf(v.x), fabsf(v.y)), fmaxf(fabsf(v.z), fabsf(v.w))));
  }
  blockmax_commit(m0, slots + 0);
  blockmax_commit(m1, slots + 1);
}

// fused prep: quant(in_w)->Wi_int, quant(out_w)->Wo_int,
// split(query) -> q_cat[row][k]: hi plane at k<1024, lo plane at k>=1024.
__global__ __launch_bounds__(256) void prep_k(const float* __restrict__ wi,
                                              const float* __restrict__ wo,
                                              const float* __restrict__ query,
                                              bf16_t* __restrict__ Wi_int,
                                              bf16_t* __restrict__ Wo_int,
                                              bf16_t* __restrict__ q_cat,
                                              const unsigned* __restrict__ slots) {
  float s0 = fmaxf(u2f(slots[0]) / 127.0f, 1e-8f);
  float s1 = fmaxf(u2f(slots[1]) / 127.0f, 1e-8f);
  const int n0 = F3 * EMB / 4, n1 = EMB * EMB / 4, n2 = NROWS * EMB / 4;
  for (int i = blockIdx.x * blockDim.x + threadIdx.x; i < n0; i += gridDim.x * blockDim.x) {
    float4 v = ((const float4*)wi)[i];
    bf16_t o[4];
    o[0] = (bf16_t)rintf(fminf(fmaxf(v.x / s0, -128.0f), 127.0f));
    o[1] = (bf16_t)rintf(fminf(fmaxf(v.y / s0, -128.0f), 127.0f));
    o[2] = (bf16_t)rintf(fminf(fmaxf(v.z / s0, -128.0f), 127.0f));
    o[3] = (bf16_t)rintf(fminf(fmaxf(v.w / s0, -128.0f), 127.0f));
    *(uint2*)&Wi_int[(size_t)i * 4] = *(uint2*)o;
  }
  for (int i = blockIdx.x * blockDim.x + threadIdx.x; i < n1; i += gridDim.x * blockDim.x) {
    float4 v = ((const float4*)wo)[i];
    bf16_t o[4];
    o[0] = (bf16_t)rintf(fminf(fmaxf(v.x / s1, -128.0f), 127.0f));
    o[1] = (bf16_t)rintf(fminf(fmaxf(v.y / s1, -128.0f), 127.0f));
    o[2] = (bf16_t)rintf(fminf(fmaxf(v.z / s1, -128.0f), 127.0f));
    o[3] = (bf16_t)rintf(fminf(fmaxf(v.w / s1, -128.0f), 127.0f));
    *(uint2*)&Wo_int[(size_t)i * 4] = *(uint2*)o;
  }
  for (int i = blockIdx.x * blockDim.x + threadIdx.x; i < n2; i += gridDim.x * blockDim.x) {
    float4 v = ((const float4*)query)[i];
    int row = i >> 8, c4 = i & 255;
    bf16_t h[4], l[4];
    float vv[4] = {v.x, v.y, v.z, v.w};
    #pragma unroll
    for (int j = 0; j < 4; ++j) {
      h[j] = (bf16_t)vv[j];
      l[j] = (bf16_t)(vv[j] - (float)h[j]);
    }
    *(uint2*)&q_cat[(size_t)row * 2048 + c4 * 4] = *(uint2*)h;
    *(uint2*)&q_cat[(size_t)row * 2048 + 1024 + c4 * 4] = *(uint2*)l;
  }
}

// merged pass after GEMM1 (both depend only on slots[2]):
// blocks [0,2048): X Q/K cols -> int bf16, fused Q-region |int| max -> slots[3]
// blocks [2048,3072): V region of X_f32 -> quant -> Vt[bh][d][token] (LDS transpose)
__global__ __launch_bounds__(256) void qxv_k(const float* __restrict__ x,
                                             bf16_t* __restrict__ y,
                                             bf16_t* __restrict__ Vt,
                                             unsigned* __restrict__ slots) {
  float s = fmaxf(u2f(slots[2]) / 127.0f, 1e-8f);
  if (blockIdx.x < 2048) {
    float qm = 0.0f;
    const int n8 = NROWS * 256;   // 2048 cols / 8 per row
    for (int i = blockIdx.x * 256 + threadIdx.x; i < n8; i += 2048 * 256) {
      int row = i >> 8, ch = i & 255;
      const float* px = x + (size_t)row * F3 + ch * 8;
      float4 v0 = *(const float4*)px;
      float4 v1 = *(const float4*)(px + 4);
      float vv[8] = {v0.x, v0.y, v0.z, v0.w, v1.x, v1.y, v1.z, v1.w};
      bf16_t o[8];
      float lm = 0.0f;
      #pragma unroll
      for (int j = 0; j < 8; ++j) {
        float q = rintf(fminf(fmaxf(vv[j] / s, -128.0f), 127.0f));
        o[j] = (bf16_t)q;
        lm = fmaxf(lm, fabsf(q));
      }
      if (ch < 128) qm = fmaxf(qm, lm);
      *(uint4*)&y[(size_t)row * F3 + ch * 8] = *(uint4*)o;
    }
    blockmax_commit(qm, slots + 3);
  } else {
    __shared__ __align__(16) bf16_t tile[64][72];
    int vb = blockIdx.x - 2048;
    int tt = vb & 31, bh = vb >> 5;
    int b = bh >> 4, h = bh & 15;
    int t = threadIdx.x;
    #pragma unroll
    for (int i = 0; i < 2; ++i) {
      int s_ = t + i * 256;
      int tok = s_ >> 3, seg = s_ & 7;
      const float* px = x + ((size_t)(tt * 64 + tok) * BATCH + b) * F3 + 2 * EMB + h * HDIM + seg * 8;
      float4 v0 = *(const float4*)px;
      float4 v1 = *(const float4*)(px + 4);
      float vv[8] = {v0.x, v0.y, v0.z, v0.w, v1.x, v1.y, v1.z, v1.w};
      bf16_t o[8];
      #pragma unroll
      for (int j = 0; j < 8; ++j)
        o[j] = (bf16_t)rintf(fminf(fmaxf(vv[j] / s, -128.0f), 127.0f));
      int segs = seg ^ (tok >> 3);
      *(uint4*)&tile[tok][segs * 8] = *(uint4*)o;
    }
    __syncthreads();
    #pragma unroll
    for (int i = 0; i < 2; ++i) {
      int s_ = t + i * 256;
      int d = s_ >> 3, tseg = s_ & 7;
      bf16_t o[8];
      #pragma unroll
      for (int e = 0; e < 8; ++e) {
        int tok = tseg * 8 + e;
        o[e] = tile[tok][(((d >> 3) ^ (tok >> 3)) << 3) | (d & 7)];
      }
      *(uint4*)&Vt[((size_t)bh * HDIM + d) * L_SEQ + tt * 64 + tseg * 8] = *(uint4*)o;
    }
  }
}

// fp32 real-valued fake-quant in place (final output)
__global__ __launch_bounds__(256) void quant_k(float* __restrict__ x, int n4,
                                               const unsigned* __restrict__ slots, int sloti) {
  float s = fmaxf(u2f(slots[sloti]) / 127.0f, 1e-8f);
  float4* x4 = (float4*)x;
  for (int i = blockIdx.x * blockDim.x + threadIdx.x; i < n4; i += gridDim.x * blockDim.x) {
    float4 v = x4[i];
    v.x = rintf(fminf(fmaxf(v.x / s, -128.0f), 127.0f)) * s;
    v.y = rintf(fminf(fmaxf(v.y / s, -128.0f), 127.0f)) * s;
    v.z = rintf(fminf(fmaxf(v.z / s, -128.0f), 127.0f)) * s;
    v.w = rintf(fminf(fmaxf(v.w / s, -128.0f), 127.0f)) * s;
    x4[i] = v;
  }
}

// fp32 -> integer-valued bf16 (heads)
__global__ __launch_bounds__(256) void quantf_k(const float* __restrict__ x,
                                                bf16_t* __restrict__ y, int n4,
                                                const unsigned* __restrict__ slots, int sloti) {
  float s = fmaxf(u2f(slots[sloti]) / 127.0f, 1e-8f);
  const float4* x4 = (const float4*)x;
  for (int i = blockIdx.x * blockDim.x + threadIdx.x; i < n4; i += gridDim.x * blockDim.x) {
    float4 v = x4[i];
    bf16_t o[4];
    o[0] = (bf16_t)rintf(fminf(fmaxf(v.x / s, -128.0f), 127.0f));
    o[1] = (bf16_t)rintf(fminf(fmaxf(v.y / s, -128.0f), 127.0f));
    o[2] = (bf16_t)rintf(fminf(fmaxf(v.z / s, -128.0f), 127.0f));
    o[3] = (bf16_t)rintf(fminf(fmaxf(v.w / s, -128.0f), 127.0f));
    *(uint2*)&y[(size_t)i * 4] = *(uint2*)o;
  }
}

// C[M,N] = A[M,KA] @ B[N,WK]^T * scale + bias[N], where B's k-index = k & (WK-1)
// (lets A carry hi|lo planes concatenated along K with W logically duplicated).
// bf16 in, f32 out. global_load_lds + 2-phase dbuf + XCD-swizzled block ids.
// Fused absmax -> slots[smax].
__global__ __launch_bounds__(256) void gemm_bt_mfma_k(const bf16_t* __restrict__ A,
                                                      const bf16_t* __restrict__ Bm,
                                                      const float* __restrict__ bias,
                                                      float* __restrict__ C,
                                                      int M, int N, int KA,
                                                      unsigned* __restrict__ slots,
                                                      int sa, int sb, int smax) {
  __shared__ __align__(16) bf16_t sbuf[2][2][128][32];
  int t = threadIdx.x;
  int w = t >> 6, l = t & 63, c15 = l & 15, g = l >> 4;
  int wr = w >> 1, wc = w & 1;
  // bijective XCD swizzle (nwg % 8 == 0 for both GEMMs)
  int nx = gridDim.x;
  int fid = blockIdx.y * nx + blockIdx.x;
  int qq = (nx * gridDim.y) >> 3;
  int swz = (fid & 7) * qq + (fid >> 3);
  int bm = (swz / nx) * 128, bn = (swz % nx) * 128;
  f32x4 acc[4][4] = {};

  auto stage = [&](int bf, int k0) {
    #pragma unroll
    for (int i = 0; i < 2; ++i) {
      int c = i * 256 + t;              // 16B-chunk id 0..511
      int row = c >> 2, sg = c & 3;
      int wb = (i * 256 + w * 64) * 8;  // wave-uniform LDS base (bf16 elems)
      gload16(&A[(size_t)(bm + row) * KA + k0 + sg * 8], &sbuf[bf][0][0][0] + wb);
      gload16(&Bm[(size_t)(bn + row) * WK + ((k0 + sg * 8) & (WK - 1))],
              &sbuf[bf][1][0][0] + wb);
    }
  };

  stage(0, 0);
  __syncthreads();
  const int nk = KA / 32;
  for (int kt = 0; kt < nk; ++kt) {
    int cur = kt & 1;
    if (kt + 1 < nk) stage(cur ^ 1, (kt + 1) * 32);
    s16x8 af[4], bf_[4];
    #pragma unroll
    for (int rt = 0; rt < 4; ++rt)
      af[rt] = *(const s16x8*)&sbuf[cur][0][wr * 64 + rt * 16 + c15][g * 8];
    #pragma unroll
    for (int ct = 0; ct < 4; ++ct)
      bf_[ct] = *(const s16x8*)&sbuf[cur][1][wc * 64 + ct * 16 + c15][g * 8];
    __builtin_amdgcn_s_setprio(1);
    #pragma unroll
    for (int rt = 0; rt < 4; ++rt)
      #pragma unroll
      for (int ct = 0; ct < 4; ++ct)
        acc[rt][ct] = MFMA16(af[rt], bf_[ct], acc[rt][ct]);
    __builtin_amdgcn_s_setprio(0);
    __syncthreads();
  }

  float s = 1.0f;
  if (sa >= 0) s *= fmaxf(u2f(slots[sa]) / 127.0f, 1e-8f);
  if (sb >= 0) s *= fmaxf(u2f(slots[sb]) / 127.0f, 1e-8f);
  float vmax = 0.0f;
  #pragma unroll
  for (int rt = 0; rt < 4; ++rt)
    #pragma unroll
    for (int r = 0; r < 4; ++r) {
      int row = bm + wr * 64 + rt * 16 + 4 * g + r;
      #pragma unroll
      for (int ct = 0; ct < 4; ++ct) {
        int col = bn + wc * 64 + ct * 16 + c15;
        float o = acc[rt][ct][r] * s + bias[col];
        vmax = fmaxf(vmax, fabsf(o));
        C[(size_t)row * N + col] = o;
      }
    }
  if (smax >= 0) blockmax_commit(vmax, slots + smax);
}

// Flash attention, swapped-operand MFMA, tau-permuted K staging (P fully in registers).
// QBLK=64, 4 waves x 16 q-rows. Grid (x=bh=32, y=qb=32): bid%8 == bh%8 -> all q-blocks
// of a head on one XCD (K/V panel 2MB/XCD L2-resident) AND 1024 blocks = 4/CU for TLP.
__global__ __launch_bounds__(256) void attn_mfma_k(const bf16_t* __restrict__ X,
                                                   const bf16_t* __restrict__ Vt,
                                                   float* __restrict__ heads,
                                                   unsigned* __restrict__ slots) {
  int bh = blockIdx.x, qb = blockIdx.y;
  int b = bh >> 4, h = bh & 15;
  int t = threadIdx.x;
  int w = t >> 6, l = t & 63, c15 = l & 15, g = l >> 4;

  float s_x = fmaxf(u2f(slots[2]) / 127.0f, 1e-8f);
  float s_q = fmaxf((u2f(slots[3]) * s_x) * 0.125f / 127.0f, 1e-8f);
  const float LOG2E = 1.4426950408889634f;
  float qsl2 = s_q * s_x * LOG2E;   // raw int-score -> log2 domain

  __shared__ __align__(16) union SmKV {
    struct { bf16_t K[2][64][64]; bf16_t V[2][64][64]; } kv;   // 32768 B
    float Ot[4][16][69];                                       // epilogue overlay
  } sm;

  // Q frags with fused requant: q2 = rint(clip(((n*s_x)*0.125)/s_q, -128, 127))
  int qrow = qb * 64 + w * 16 + c15;
  const bf16_t* qbase = X + ((size_t)qrow * BATCH + b) * F3 + h * HDIM;
  s16x8 qf0, qf1;
  {
    bf16_t qt[8];
    #pragma unroll
    for (int half = 0; half < 2; ++half) {
      *(uint4*)qt = *(const uint4*)(qbase + half * 32 + g * 8);
      #pragma unroll
      for (int j = 0; j < 8; ++j) {
        float q = ((float)qt[j] * s_x) * 0.125f;
        qt[j] = (bf16_t)rintf(fminf(fmaxf(q / s_q, -128.0f), 127.0f));
      }
      if (half == 0) qf0 = *(s16x8*)qt; else qf1 = *(s16x8*)qt;
    }
  }

  const size_t tokstride = (size_t)BATCH * F3;
  const bf16_t* kbase = X + (size_t)b * F3 + EMB + h * HDIM;
  const bf16_t* vbase = Vt + (size_t)bh * HDIM * L_SEQ;

  // stage tile kt into buffer buf: linear LDS dest, tau+XOR-swizzle baked into global src
  auto stage = [&](int buf, int kt) {
    #pragma unroll
    for (int i = 0; i < 2; ++i) {
      int c = i * 256 + t;              // chunk 0..511 of K[buf]
      int a = c >> 3, blk = c & 7;
      int kap = (a & 0x20) | ((a & 0x10) >> 2) | ((a & 0x0C) << 1) | (a & 3);
      gload16(kbase + (size_t)(kt * 64 + kap) * tokstride + (blk ^ (a & 7)) * 8,
              &sm.kv.K[buf][0][0] + (i * 256 + w * 64) * 8);
    }
    #pragma unroll
    for (int i = 0; i < 2; ++i) {
      int c = i * 256 + t;              // chunk 0..511 of V[buf]
      int d = c >> 3, blk = c & 7;
      gload16(vbase + (size_t)d * L_SEQ + kt * 64 + (blk ^ (d & 7)) * 8,
              &sm.kv.V[buf][0][0] + (i * 256 + w * 64) * 8);
    }
  };

  f32x4 acc_o[4] = {};
  float m_prev = -INFINITY, lsum = 0.0f;
  int sw = c15 & 7;                     // read swizzle (row&7 == c15&7 for all frag rows)

  stage(0, 0);
  __syncthreads();

  const int NT = L_SEQ / 64;
  int cur = 0;
  for (int kt = 0; kt < NT; ++kt) {
    if (kt + 1 < NT) stage(cur ^ 1, kt + 1);

    // QK^T swapped: A=K (rows = tau-permuted tokens), B=Q (cols=q=c15)
    f32x4 accs[4] = {};
    __builtin_amdgcn_s_setprio(1);
    #pragma unroll
    for (int ct = 0; ct < 4; ++ct) {
      const bf16_t* krow = &sm.kv.K[cur][ct * 16 + c15][0];
      s16x8 kf0 = *(const s16x8*)(krow + (g ^ sw) * 8);
      s16x8 kf1 = *(const s16x8*)(krow + ((g | 4) ^ sw) * 8);
      accs[ct] = MFMA16(kf0, qf0, accs[ct]);
      accs[ct] = MFMA16(kf1, qf1, accs[ct]);
    }
    __builtin_amdgcn_s_setprio(0);

    // in-register softmax for q=c15 (lane holds 16 of 64 scores); max3 tree (bit-identical)
    float t0 = max3f(accs[0][0], accs[0][1], accs[0][2]);
    float t1 = max3f(accs[0][3], accs[1][0], accs[1][1]);
    float t2 = max3f(accs[1][2], accs[1][3], accs[2][0]);
    float t3 = max3f(accs[2][1], accs[2][2], accs[2][3]);
    float t4 = max3f(accs[3][0], accs[3][1], accs[3][2]);
    float pm = fmaxf(max3f(t0, t1, t2), max3f(t3, t4, accs[3][3]));
    pm = fmaxf(pm, __shfl_xor(pm, 16));
    pm = fmaxf(pm, __shfl_xor(pm, 32));
    float mnew = fmaxf(m_prev, pm);
    float f_ = __builtin_amdgcn_exp2f((m_prev - mnew) * qsl2);
    float mq = mnew * qsl2;
    float ps = 0.0f;
    bf16_t hh[2][8], ll[2][8];
    #pragma unroll
    for (int ct = 0; ct < 4; ++ct) {
      float p[4];
      #pragma unroll
      for (int r = 0; r < 4; ++r) p[r] = __builtin_amdgcn_exp2f(fmaf(accs[ct][r], qsl2, -mq));
      ps += (p[0] + p[1]) + (p[2] + p[3]);
      #pragma unroll
      for (int r = 0; r < 4; ++r) {
        bf16_t hi = (bf16_t)p[r];
        hh[ct >> 1][(ct & 1) * 4 + r] = hi;
        ll[ct >> 1][(ct & 1) * 4 + r] = (bf16_t)(p[r] - (float)hi);
      }
    }
    lsum = lsum * f_ + ps;
    m_prev = mnew;

    // rescale O^T (factor lane-local in q=c15); skip when uniformly 1
    if (!__all(f_ == 1.0f)) {
      #pragma unroll
      for (int dt = 0; dt < 4; ++dt)
        #pragma unroll
        for (int r = 0; r < 4; ++r) acc_o[dt][r] *= f_;
    }

    // PV swapped: A=V^T, B=P (frags assembled in registers via tau alignment)
    s16x8 pfh0 = *(s16x8*)hh[0], pfh1 = *(s16x8*)hh[1];
    s16x8 pfl0 = *(s16x8*)ll[0], pfl1 = *(s16x8*)ll[1];
    __builtin_amdgcn_s_setprio(1);
    #pragma unroll
    for (int dt = 0; dt < 4; ++dt) {
      const bf16_t* vrow = &sm.kv.V[cur][dt * 16 + c15][0];
      s16x8 vf0 = *(const s16x8*)(vrow + (g ^ sw) * 8);
      s16x8 vf1 = *(const s16x8*)(vrow + ((g | 4) ^ sw) * 8);
      acc_o[dt] = MFMA16(vf0, pfh0, acc_o[dt]);
      acc_o[dt] = MFMA16(vf1, pfh1, acc_o[dt]);
      acc_o[dt] = MFMA16(vf0, pfl0, acc_o[dt]);
      acc_o[dt] = MFMA16(vf1, pfl1, acc_o[dt]);
    }
    __builtin_amdgcn_s_setprio(0);

    __syncthreads();   // drains gload_lds (vmcnt) -> next buffer staged; cur reads done
    cur ^= 1;
  }

  lsum += __shfl_xor(lsum, 16);
  lsum += __shfl_xor(lsum, 32);
  float inv = s_x / lsum;

  // O^T -> Ot[w][q][d] (overlay on K/V union; barrier above guarantees reads done)
  float hm = 0.0f;
  #pragma unroll
  for (int dt = 0; dt < 4; ++dt)
    #pragma unroll
    for (int r = 0; r < 4; ++r) {
      float o = acc_o[dt][r] * inv;
      hm = fmaxf(hm, fabsf(o));
      sm.Ot[w][c15][dt * 16 + 4 * g + r] = o;
    }
  int ql = l >> 2, cs = l & 3;
  #pragma unroll
  for (int j = 0; j < 4; ++j) {
    int cch = cs + 4 * j;
    float4 v = *(const float4*)&sm.Ot[w][ql][cch * 4];
    int row = qb * 64 + w * 16 + ql;
    *(float4*)&heads[((size_t)row * BATCH + b) * EMB + h * HDIM + cch * 4] = v;
  }
  blockmax_commit(hm, slots + 4);
}

extern "C" void kernel_launch(void* const* d_in, const int* in_sizes, int n_in,
                              void* d_out, int out_size, void* d_ws, size_t ws_size,
                              hipStream_t stream) {
  (void)in_sizes; (void)n_in; (void)out_size; (void)ws_size;
  const float* query = (const float*)d_in[0];
  const float* in_w  = (const float*)d_in[3];
  const float* in_b  = (const float*)d_in[4];
  const float* out_w = (const float*)d_in[5];
  const float* out_b = (const float*)d_in[6];
  float* out = (float*)d_out;

  unsigned* slots = (unsigned*)d_ws;
  char* p = (char*)d_ws + 256;
  bf16_t* q_cat  = (bf16_t*)p;                  p += (size_t)NROWS * 2048 * 2;  // 16 MB
  bf16_t* Wi_int = (bf16_t*)p;                  p += (size_t)F3 * EMB * 2;      // 6 MB
  bf16_t* Wo_int = (bf16_t*)p;                  p += (size_t)EMB * EMB * 2;     // 2 MB
  float*  X_f32  = (float*)p;                   p += (size_t)NROWS * F3 * 4;    // 48 MB
  bf16_t* X_int  = (bf16_t*)p;                                                  // 24 MB
  bf16_t* Vt     = q_cat;              // q_cat dead after GEMM1; reuse (8 MB)
  bf16_t* heads_int = (bf16_t*)X_f32;  // X_f32 dead after qxv
  float*  heads_f32 = out;             // d_out doubles as heads staging

  hipMemsetAsync(d_ws, 0, 256, stream);

  dim3 b256(256);
  // weight absmax (one launch), then fused quant-weights + query split (K-concat planes)
  wabsmax_k<<<768, b256, 0, stream>>>(in_w, out_w, slots);
  prep_k<<<1024, b256, 0, stream>>>(in_w, out_w, query, Wi_int, Wo_int, q_cat, slots);

  // GEMM1: X = q_cat[4096x2048] @ dup(Wi_int)^T * s_wi + in_b ; fused absmax(X) -> slot2
  gemm_bt_mfma_k<<<dim3(F3 / 128, NROWS / 128), b256, 0, stream>>>(
      q_cat, Wi_int, in_b, X_f32, NROWS, F3, 2048, slots, -1, 0, 2);

  // merged: X Q/K cols -> int bf16 (+slot3) and V quant+transpose -> Vt
  qxv_k<<<3072, b256, 0, stream>>>(X_f32, X_int, Vt, slots);

  // attention (q requant fused) -> heads_f32 (= d_out), fused absmax(heads) -> slot4
  attn_mfma_k<<<dim3(BATCH * NH, L_SEQ / 64), b256, 0, stream>>>(X_int, Vt, heads_f32, slots);

  // heads -> int bf16
  quantf_k<<<1024, b256, 0, stream>>>(heads_f32, heads_int, NROWS * EMB / 4, slots, 4);

  // GEMM2: y = heads_int @ Wo_int^T * (s_h*s_wo) + out_b ; fused absmax(y) -> slot5
  gemm_bt_mfma_k<<<dim3(EMB / 128, NROWS / 128), b256, 0, stream>>>(
      heads_int, Wo_int, out_b, out, NROWS, EMB, 1024, slots, 4, 1, 5);

  // final fake-quant in place
  quant_k<<<1024, b256, 0, stream>>>(out, NROWS * EMB / 4, slots, 5);
}

// Round 14
// 239.883 us; speedup vs baseline: 1.0524x; 1.0524x over previous
//
#include <hip/hip_runtime.h>
#include <math.h>

#define L_SEQ 2048
#define BATCH 2
#define EMB 1024
#define NH 16
#define HDIM 64
#define F3 3072
#define NROWS 4096   // L_SEQ * BATCH

typedef __bf16 bf16_t;
typedef short s16x8 __attribute__((ext_vector_type(8)));
typedef float f32x4 __attribute__((ext_vector_type(4)));

#define MFMA16(a, b, c) __builtin_amdgcn_mfma_f32_16x16x32_bf16(a, b, c, 0, 0, 0)

// ws slots (uint bits of fp32 absmax):
// [0]=absmax(in_w) [1]=absmax(out_w) [2]=absmax(X) [3]=max|int| of Xq Q-region
// [4]=absmax(heads) [5]=absmax(y)

__device__ __forceinline__ float u2f(unsigned u) { return __uint_as_float(u); }

__device__ __forceinline__ float max3f(float a, float b, float c) {
  return fmaxf(fmaxf(a, b), c);   // clang fuses to v_max3_f32; fmax exactly associative
}

__device__ __forceinline__ void gload16(const bf16_t* g, bf16_t* lds) {
  __builtin_amdgcn_global_load_lds((const __attribute__((address_space(1))) void*)g,
                                   (__attribute__((address_space(3))) void*)lds, 16, 0, 0);
}

__device__ __forceinline__ void blockmax_commit(float m, unsigned* slot) {
  #pragma unroll
  for (int o = 1; o < 64; o <<= 1) m = fmaxf(m, __shfl_xor(m, o));
  __shared__ float sm_[4];
  if ((threadIdx.x & 63) == 0) sm_[threadIdx.x >> 6] = m;
  __syncthreads();
  if (threadIdx.x == 0) {
    float mm = fmaxf(fmaxf(sm_[0], sm_[1]), fmaxf(sm_[2], sm_[3]));
    atomicMax(slot, __float_as_uint(mm));
  }
}

// absmax of in_w -> slot0 and out_w -> slot1, one launch
__global__ __launch_bounds__(256) void wabsmax_k(const float* __restrict__ wi,
                                                 const float* __restrict__ wo,
                                                 unsigned* __restrict__ slots) {
  float m0 = 0.0f, m1 = 0.0f;
  const int n0 = F3 * EMB / 4, n1 = EMB * EMB / 4;
  for (int i = blockIdx.x * blockDim.x + threadIdx.x; i < n0; i += gridDim.x * blockDim.x) {
    float4 v = ((const float4*)wi)[i];
    m0 = fmaxf(m0, fmaxf(fmaxf(fabsf(v.x), fabsf(v.y)), fmaxf(fabsf(v.z), fabsf(v.w))));
  }
  for (int i = blockIdx.x * blockDim.x + threadIdx.x; i < n1; i += gridDim.x * blockDim.x) {
    float4 v = ((const float4*)wo)[i];
    m1 = fmaxf(m1, fmaxf(fmaxf(fabsf(v.x), fabsf(v.y)), fmaxf(fabsf(v.z), fabsf(v.w))));
  }
  blockmax_commit(m0, slots + 0);
  blockmax_commit(m1, slots + 1);
}

// fused prep: quant(in_w)->Wi_int, quant(out_w)->Wo_int, split(query)->q_hi/q_lo
__global__ __launch_bounds__(256) void prep_k(const float* __restrict__ wi,
                                              const float* __restrict__ wo,
                                              const float* __restrict__ query,
                                              bf16_t* __restrict__ Wi_int,
                                              bf16_t* __restrict__ Wo_int,
                                              bf16_t* __restrict__ q_hi,
                                              bf16_t* __restrict__ q_lo,
                                              const unsigned* __restrict__ slots) {
  float s0 = fmaxf(u2f(slots[0]) / 127.0f, 1e-8f);
  float s1 = fmaxf(u2f(slots[1]) / 127.0f, 1e-8f);
  const int n0 = F3 * EMB / 4, n1 = EMB * EMB / 4, n2 = NROWS * EMB / 4;
  for (int i = blockIdx.x * blockDim.x + threadIdx.x; i < n0; i += gridDim.x * blockDim.x) {
    float4 v = ((const float4*)wi)[i];
    bf16_t o[4];
    o[0] = (bf16_t)rintf(fminf(fmaxf(v.x / s0, -128.0f), 127.0f));
    o[1] = (bf16_t)rintf(fminf(fmaxf(v.y / s0, -128.0f), 127.0f));
    o[2] = (bf16_t)rintf(fminf(fmaxf(v.z / s0, -128.0f), 127.0f));
    o[3] = (bf16_t)rintf(fminf(fmaxf(v.w / s0, -128.0f), 127.0f));
    *(uint2*)&Wi_int[(size_t)i * 4] = *(uint2*)o;
  }
  for (int i = blockIdx.x * blockDim.x + threadIdx.x; i < n1; i += gridDim.x * blockDim.x) {
    float4 v = ((const float4*)wo)[i];
    bf16_t o[4];
    o[0] = (bf16_t)rintf(fminf(fmaxf(v.x / s1, -128.0f), 127.0f));
    o[1] = (bf16_t)rintf(fminf(fmaxf(v.y / s1, -128.0f), 127.0f));
    o[2] = (bf16_t)rintf(fminf(fmaxf(v.z / s1, -128.0f), 127.0f));
    o[3] = (bf16_t)rintf(fminf(fmaxf(v.w / s1, -128.0f), 127.0f));
    *(uint2*)&Wo_int[(size_t)i * 4] = *(uint2*)o;
  }
  for (int i = blockIdx.x * blockDim.x + threadIdx.x; i < n2; i += gridDim.x * blockDim.x) {
    float4 v = ((const float4*)query)[i];
    bf16_t h[4], l[4];
    float vv[4] = {v.x, v.y, v.z, v.w};
    #pragma unroll
    for (int j = 0; j < 4; ++j) {
      h[j] = (bf16_t)vv[j];
      l[j] = (bf16_t)(vv[j] - (float)h[j]);
    }
    *(uint2*)&q_hi[(size_t)i * 4] = *(uint2*)h;
    *(uint2*)&q_lo[(size_t)i * 4] = *(uint2*)l;
  }
}

// merged pass after GEMM1 (both depend only on slots[2]):
// blocks [0,2048): X Q/K cols -> int bf16, fused Q-region |int| max -> slots[3]
// blocks [2048,3072): V region of X_f32 -> quant -> Vt[bh][d][token] (LDS transpose)
__global__ __launch_bounds__(256) void qxv_k(const float* __restrict__ x,
                                             bf16_t* __restrict__ y,
                                             bf16_t* __restrict__ Vt,
                                             unsigned* __restrict__ slots) {
  float s = fmaxf(u2f(slots[2]) / 127.0f, 1e-8f);
  if (blockIdx.x < 2048) {
    float qm = 0.0f;
    const int n8 = NROWS * 256;   // 2048 cols / 8 per row
    for (int i = blockIdx.x * 256 + threadIdx.x; i < n8; i += 2048 * 256) {
      int row = i >> 8, ch = i & 255;
      const float* px = x + (size_t)row * F3 + ch * 8;
      float4 v0 = *(const float4*)px;
      float4 v1 = *(const float4*)(px + 4);
      float vv[8] = {v0.x, v0.y, v0.z, v0.w, v1.x, v1.y, v1.z, v1.w};
      bf16_t o[8];
      float lm = 0.0f;
      #pragma unroll
      for (int j = 0; j < 8; ++j) {
        float q = rintf(fminf(fmaxf(vv[j] / s, -128.0f), 127.0f));
        o[j] = (bf16_t)q;
        lm = fmaxf(lm, fabsf(q));
      }
      if (ch < 128) qm = fmaxf(qm, lm);
      *(uint4*)&y[(size_t)row * F3 + ch * 8] = *(uint4*)o;
    }
    blockmax_commit(qm, slots + 3);
  } else {
    __shared__ __align__(16) bf16_t tile[64][72];
    int vb = blockIdx.x - 2048;
    int tt = vb & 31, bh = vb >> 5;
    int b = bh >> 4, h = bh & 15;
    int t = threadIdx.x;
    #pragma unroll
    for (int i = 0; i < 2; ++i) {
      int s_ = t + i * 256;
      int tok = s_ >> 3, seg = s_ & 7;
      const float* px = x + ((size_t)(tt * 64 + tok) * BATCH + b) * F3 + 2 * EMB + h * HDIM + seg * 8;
      float4 v0 = *(const float4*)px;
      float4 v1 = *(const float4*)(px + 4);
      float vv[8] = {v0.x, v0.y, v0.z, v0.w, v1.x, v1.y, v1.z, v1.w};
      bf16_t o[8];
      #pragma unroll
      for (int j = 0; j < 8; ++j)
        o[j] = (bf16_t)rintf(fminf(fmaxf(vv[j] / s, -128.0f), 127.0f));
      int segs = seg ^ (tok >> 3);
      *(uint4*)&tile[tok][segs * 8] = *(uint4*)o;
    }
    __syncthreads();
    #pragma unroll
    for (int i = 0; i < 2; ++i) {
      int s_ = t + i * 256;
      int d = s_ >> 3, tseg = s_ & 7;
      bf16_t o[8];
      #pragma unroll
      for (int e = 0; e < 8; ++e) {
        int tok = tseg * 8 + e;
        o[e] = tile[tok][(((d >> 3) ^ (tok >> 3)) << 3) | (d & 7)];
      }
      *(uint4*)&Vt[((size_t)bh * HDIM + d) * L_SEQ + tt * 64 + tseg * 8] = *(uint4*)o;
    }
  }
}

// fp32 real-valued fake-quant in place (final output)
__global__ __launch_bounds__(256) void quant_k(float* __restrict__ x, int n4,
                                               const unsigned* __restrict__ slots, int sloti) {
  float s = fmaxf(u2f(slots[sloti]) / 127.0f, 1e-8f);
  float4* x4 = (float4*)x;
  for (int i = blockIdx.x * blockDim.x + threadIdx.x; i < n4; i += gridDim.x * blockDim.x) {
    float4 v = x4[i];
    v.x = rintf(fminf(fmaxf(v.x / s, -128.0f), 127.0f)) * s;
    v.y = rintf(fminf(fmaxf(v.y / s, -128.0f), 127.0f)) * s;
    v.z = rintf(fminf(fmaxf(v.z / s, -128.0f), 127.0f)) * s;
    v.w = rintf(fminf(fmaxf(v.w / s, -128.0f), 127.0f)) * s;
    x4[i] = v;
  }
}

// fp32 -> integer-valued bf16 (heads)
__global__ __launch_bounds__(256) void quantf_k(const float* __restrict__ x,
                                                bf16_t* __restrict__ y, int n4,
                                                const unsigned* __restrict__ slots, int sloti) {
  float s = fmaxf(u2f(slots[sloti]) / 127.0f, 1e-8f);
  const float4* x4 = (const float4*)x;
  for (int i = blockIdx.x * blockDim.x + threadIdx.x; i < n4; i += gridDim.x * blockDim.x) {
    float4 v = x4[i];
    bf16_t o[4];
    o[0] = (bf16_t)rintf(fminf(fmaxf(v.x / s, -128.0f), 127.0f));
    o[1] = (bf16_t)rintf(fminf(fmaxf(v.y / s, -128.0f), 127.0f));
    o[2] = (bf16_t)rintf(fminf(fmaxf(v.z / s, -128.0f), 127.0f));
    o[3] = (bf16_t)rintf(fminf(fmaxf(v.w / s, -128.0f), 127.0f));
    *(uint2*)&y[(size_t)i * 4] = *(uint2*)o;
  }
}

// C[M,N] = (sum_p A_p[M,K]) @ B[N,K]^T * scale + bias[N]; bf16 in, f32 out.
// 128x128 tile. global_load_lds + 2-phase dbuf + XCD swizzle. Fused absmax -> slots[smax].
template <int NPARTS>
__global__ __launch_bounds__(256) void gemm_bt_mfma_k(const bf16_t* __restrict__ A0,
                                                      const bf16_t* __restrict__ A1,
                                                      const bf16_t* __restrict__ Bm,
                                                      const float* __restrict__ bias,
                                                      float* __restrict__ C,
                                                      int M, int N, int K,
                                                      unsigned* __restrict__ slots,
                                                      int sa, int sb, int smax) {
  __shared__ __align__(16) bf16_t sbuf[2][NPARTS + 1][128][32];
  int t = threadIdx.x;
  int w = t >> 6, l = t & 63, c15 = l & 15, g = l >> 4;
  int wr = w >> 1, wc = w & 1;
  // bijective XCD swizzle (nwg % 8 == 0 for both GEMMs)
  int nx = gridDim.x;
  int fid = blockIdx.y * nx + blockIdx.x;
  int qq = (nx * gridDim.y) >> 3;
  int swz = (fid & 7) * qq + (fid >> 3);
  int bm = (swz / nx) * 128, bn = (swz % nx) * 128;
  f32x4 acc[4][4] = {};

  auto stage = [&](int bf, int k0) {
    #pragma unroll
    for (int i = 0; i < 2; ++i) {
      int c = i * 256 + t;              // 16B-chunk id 0..511
      int row = c >> 2, sg = c & 3;
      int wb = (i * 256 + w * 64) * 8;  // wave-uniform LDS base (bf16 elems)
      gload16(&A0[(size_t)(bm + row) * K + k0 + sg * 8], &sbuf[bf][0][0][0] + wb);
      if (NPARTS == 2)
        gload16(&A1[(size_t)(bm + row) * K + k0 + sg * 8], &sbuf[bf][1][0][0] + wb);
      gload16(&Bm[(size_t)(bn + row) * K + k0 + sg * 8], &sbuf[bf][NPARTS][0][0] + wb);
    }
  };

  stage(0, 0);
  __syncthreads();
  const int nk = K / 32;
  for (int kt = 0; kt < nk; ++kt) {
    int cur = kt & 1;
    if (kt + 1 < nk) stage(cur ^ 1, (kt + 1) * 32);
    s16x8 af[NPARTS][4], bf_[4];
    #pragma unroll
    for (int rt = 0; rt < 4; ++rt) {
      af[0][rt] = *(const s16x8*)&sbuf[cur][0][wr * 64 + rt * 16 + c15][g * 8];
      if (NPARTS == 2) af[1][rt] = *(const s16x8*)&sbuf[cur][1][wr * 64 + rt * 16 + c15][g * 8];
    }
    #pragma unroll
    for (int ct = 0; ct < 4; ++ct)
      bf_[ct] = *(const s16x8*)&sbuf[cur][NPARTS][wc * 64 + ct * 16 + c15][g * 8];
    __builtin_amdgcn_s_setprio(1);
    #pragma unroll
    for (int rt = 0; rt < 4; ++rt)
      #pragma unroll
      for (int ct = 0; ct < 4; ++ct) {
        acc[rt][ct] = MFMA16(af[0][rt], bf_[ct], acc[rt][ct]);
        if (NPARTS == 2) acc[rt][ct] = MFMA16(af[1][rt], bf_[ct], acc[rt][ct]);
      }
    __builtin_amdgcn_s_setprio(0);
    __syncthreads();
  }

  float s = 1.0f;
  if (sa >= 0) s *= fmaxf(u2f(slots[sa]) / 127.0f, 1e-8f);
  if (sb >= 0) s *= fmaxf(u2f(slots[sb]) / 127.0f, 1e-8f);
  float vmax = 0.0f;
  #pragma unroll
  for (int rt = 0; rt < 4; ++rt)
    #pragma unroll
    for (int r = 0; r < 4; ++r) {
      int row = bm + wr * 64 + rt * 16 + 4 * g + r;
      #pragma unroll
      for (int ct = 0; ct < 4; ++ct) {
        int col = bn + wc * 64 + ct * 16 + c15;
        float o = acc[rt][ct][r] * s + bias[col];
        vmax = fmaxf(vmax, fabsf(o));
        C[(size_t)row * N + col] = o;
      }
    }
  if (smax >= 0) blockmax_commit(vmax, slots + smax);
}

// 64x128-tile variant for small-N GEMM2: grid 8x64=512 blocks -> 6 blocks/CU (24 KB LDS),
// same BK=32 2-phase structure; per-output K-chain identical -> bit-identical results.
__global__ __launch_bounds__(256) void gemm_m64_k(const bf16_t* __restrict__ A,
                                                  const bf16_t* __restrict__ Bm,
                                                  const float* __restrict__ bias,
                                                  float* __restrict__ C,
                                                  int M, int N, int K,
                                                  unsigned* __restrict__ slots,
                                                  int sa, int sb, int smax) {
  __shared__ __align__(16) bf16_t As[2][64][32];
  __shared__ __align__(16) bf16_t Bs[2][128][32];
  int t = threadIdx.x;
  int w = t >> 6, l = t & 63, c15 = l & 15, g = l >> 4;
  int wr = w >> 1, wc = w & 1;   // wave: 32 rows x 64 cols of the 64x128 tile
  int nx = gridDim.x;
  int fid = blockIdx.y * nx + blockIdx.x;
  int qq = (nx * gridDim.y) >> 3;
  int swz = (fid & 7) * qq + (fid >> 3);
  int bm = (swz / nx) * 64, bn = (swz % nx) * 128;
  f32x4 acc[2][4] = {};

  auto stage = [&](int bf, int k0) {
    {
      int c = t;                        // A: 256 chunks (64 rows x 4)
      int row = c >> 2, sg = c & 3;
      gload16(&A[(size_t)(bm + row) * K + k0 + sg * 8], &As[bf][0][0] + (w * 64) * 8);
    }
    #pragma unroll
    for (int i = 0; i < 2; ++i) {       // B: 512 chunks (128 rows x 4)
      int c = i * 256 + t;
      int row = c >> 2, sg = c & 3;
      gload16(&Bm[(size_t)(bn + row) * K + k0 + sg * 8],
              &Bs[bf][0][0] + (i * 256 + w * 64) * 8);
    }
  };

  stage(0, 0);
  __syncthreads();
  const int nk = K / 32;
  for (int kt = 0; kt < nk; ++kt) {
    int cur = kt & 1;
    if (kt + 1 < nk) stage(cur ^ 1, (kt + 1) * 32);
    s16x8 af[2], bf_[4];
    #pragma unroll
    for (int rt = 0; rt < 2; ++rt)
      af[rt] = *(const s16x8*)&As[cur][wr * 32 + rt * 16 + c15][g * 8];
    #pragma unroll
    for (int ct = 0; ct < 4; ++ct)
      bf_[ct] = *(const s16x8*)&Bs[cur][wc * 64 + ct * 16 + c15][g * 8];
    __builtin_amdgcn_s_setprio(1);
    #pragma unroll
    for (int rt = 0; rt < 2; ++rt)
      #pragma unroll
      for (int ct = 0; ct < 4; ++ct)
        acc[rt][ct] = MFMA16(af[rt], bf_[ct], acc[rt][ct]);
    __builtin_amdgcn_s_setprio(0);
    __syncthreads();
  }

  float s = 1.0f;
  if (sa >= 0) s *= fmaxf(u2f(slots[sa]) / 127.0f, 1e-8f);
  if (sb >= 0) s *= fmaxf(u2f(slots[sb]) / 127.0f, 1e-8f);
  float vmax = 0.0f;
  #pragma unroll
  for (int rt = 0; rt < 2; ++rt)
    #pragma unroll
    for (int r = 0; r < 4; ++r) {
      int row = bm + wr * 32 + rt * 16 + 4 * g + r;
      #pragma unroll
      for (int ct = 0; ct < 4; ++ct) {
        int col = bn + wc * 64 + ct * 16 + c15;
        float o = acc[rt][ct][r] * s + bias[col];
        vmax = fmaxf(vmax, fabsf(o));
        C[(size_t)row * N + col] = o;
      }
    }
  if (smax >= 0) blockmax_commit(vmax, slots + smax);
}

// Flash attention, swapped-operand MFMA, tau-permuted K staging (P fully in registers).
// QBLK=64, 4 waves x 16 q-rows. Grid (x=bh=32, y=qb=32): bid%8 == bh%8 -> all q-blocks
// of a head on one XCD (K/V panel 2MB/XCD L2-resident) AND 1024 blocks = 4/CU for TLP.
__global__ __launch_bounds__(256) void attn_mfma_k(const bf16_t* __restrict__ X,
                                                   const bf16_t* __restrict__ Vt,
                                                   float* __restrict__ heads,
                                                   unsigned* __restrict__ slots) {
  int bh = blockIdx.x, qb = blockIdx.y;
  int b = bh >> 4, h = bh & 15;
  int t = threadIdx.x;
  int w = t >> 6, l = t & 63, c15 = l & 15, g = l >> 4;

  float s_x = fmaxf(u2f(slots[2]) / 127.0f, 1e-8f);
  float s_q = fmaxf((u2f(slots[3]) * s_x) * 0.125f / 127.0f, 1e-8f);
  const float LOG2E = 1.4426950408889634f;
  float qsl2 = s_q * s_x * LOG2E;   // raw int-score -> log2 domain

  __shared__ __align__(16) union SmKV {
    struct { bf16_t K[2][64][64]; bf16_t V[2][64][64]; } kv;   // 32768 B
    float Ot[4][16][69];                                       // epilogue overlay
  } sm;

  // Q frags with fused requant: q2 = rint(clip(((n*s_x)*0.125)/s_q, -128, 127))
  int qrow = qb * 64 + w * 16 + c15;
  const bf16_t* qbase = X + ((size_t)qrow * BATCH + b) * F3 + h * HDIM;
  s16x8 qf0, qf1;
  {
    bf16_t qt[8];
    #pragma unroll
    for (int half = 0; half < 2; ++half) {
      *(uint4*)qt = *(const uint4*)(qbase + half * 32 + g * 8);
      #pragma unroll
      for (int j = 0; j < 8; ++j) {
        float q = ((float)qt[j] * s_x) * 0.125f;
        qt[j] = (bf16_t)rintf(fminf(fmaxf(q / s_q, -128.0f), 127.0f));
      }
      if (half == 0) qf0 = *(s16x8*)qt; else qf1 = *(s16x8*)qt;
    }
  }

  const size_t tokstride = (size_t)BATCH * F3;
  const bf16_t* kbase = X + (size_t)b * F3 + EMB + h * HDIM;
  const bf16_t* vbase = Vt + (size_t)bh * HDIM * L_SEQ;

  // stage tile kt into buffer buf: linear LDS dest, tau+XOR-swizzle baked into global src
  auto stage = [&](int buf, int kt) {
    #pragma unroll
    for (int i = 0; i < 2; ++i) {
      int c = i * 256 + t;              // chunk 0..511 of K[buf]
      int a = c >> 3, blk = c & 7;
      int kap = (a & 0x20) | ((a & 0x10) >> 2) | ((a & 0x0C) << 1) | (a & 3);
      gload16(kbase + (size_t)(kt * 64 + kap) * tokstride + (blk ^ (a & 7)) * 8,
              &sm.kv.K[buf][0][0] + (i * 256 + w * 64) * 8);
    }
    #pragma unroll
    for (int i = 0; i < 2; ++i) {
      int c = i * 256 + t;              // chunk 0..511 of V[buf]
      int d = c >> 3, blk = c & 7;
      gload16(vbase + (size_t)d * L_SEQ + kt * 64 + (blk ^ (d & 7)) * 8,
              &sm.kv.V[buf][0][0] + (i * 256 + w * 64) * 8);
    }
  };

  f32x4 acc_o[4] = {};
  float m_prev = -INFINITY, lsum = 0.0f;
  int sw = c15 & 7;                     // read swizzle (row&7 == c15&7 for all frag rows)

  stage(0, 0);
  __syncthreads();

  const int NT = L_SEQ / 64;
  int cur = 0;
  for (int kt = 0; kt < NT; ++kt) {
    if (kt + 1 < NT) stage(cur ^ 1, kt + 1);

    // QK^T swapped: A=K (rows = tau-permuted tokens), B=Q (cols=q=c15)
    f32x4 accs[4] = {};
    __builtin_amdgcn_s_setprio(1);
    #pragma unroll
    for (int ct = 0; ct < 4; ++ct) {
      const bf16_t* krow = &sm.kv.K[cur][ct * 16 + c15][0];
      s16x8 kf0 = *(const s16x8*)(krow + (g ^ sw) * 8);
      s16x8 kf1 = *(const s16x8*)(krow + ((g | 4) ^ sw) * 8);
      accs[ct] = MFMA16(kf0, qf0, accs[ct]);
      accs[ct] = MFMA16(kf1, qf1, accs[ct]);
    }
    __builtin_amdgcn_s_setprio(0);

    // in-register softmax for q=c15 (lane holds 16 of 64 scores); max3 tree (bit-identical)
    float t0 = max3f(accs[0][0], accs[0][1], accs[0][2]);
    float t1 = max3f(accs[0][3], accs[1][0], accs[1][1]);
    float t2 = max3f(accs[1][2], accs[1][3], accs[2][0]);
    float t3 = max3f(accs[2][1], accs[2][2], accs[2][3]);
    float t4 = max3f(accs[3][0], accs[3][1], accs[3][2]);
    float pm = fmaxf(max3f(t0, t1, t2), max3f(t3, t4, accs[3][3]));
    pm = fmaxf(pm, __shfl_xor(pm, 16));
    pm = fmaxf(pm, __shfl_xor(pm, 32));
    float mnew = fmaxf(m_prev, pm);
    float f_ = __builtin_amdgcn_exp2f((m_prev - mnew) * qsl2);
    float mq = mnew * qsl2;
    float ps = 0.0f;
    bf16_t hh[2][8], ll[2][8];
    #pragma unroll
    for (int ct = 0; ct < 4; ++ct) {
      float p[4];
      #pragma unroll
      for (int r = 0; r < 4; ++r) p[r] = __builtin_amdgcn_exp2f(fmaf(accs[ct][r], qsl2, -mq));
      ps += (p[0] + p[1]) + (p[2] + p[3]);
      #pragma unroll
      for (int r = 0; r < 4; ++r) {
        bf16_t hi = (bf16_t)p[r];
        hh[ct >> 1][(ct & 1) * 4 + r] = hi;
        ll[ct >> 1][(ct & 1) * 4 + r] = (bf16_t)(p[r] - (float)hi);
      }
    }
    lsum = lsum * f_ + ps;
    m_prev = mnew;

    // rescale O^T (factor lane-local in q=c15); skip when uniformly 1
    if (!__all(f_ == 1.0f)) {
      #pragma unroll
      for (int dt = 0; dt < 4; ++dt)
        #pragma unroll
        for (int r = 0; r < 4; ++r) acc_o[dt][r] *= f_;
    }

    // PV swapped: A=V^T, B=P (frags assembled in registers via tau alignment)
    s16x8 pfh0 = *(s16x8*)hh[0], pfh1 = *(s16x8*)hh[1];
    s16x8 pfl0 = *(s16x8*)ll[0], pfl1 = *(s16x8*)ll[1];
    __builtin_amdgcn_s_setprio(1);
    #pragma unroll
    for (int dt = 0; dt < 4; ++dt) {
      const bf16_t* vrow = &sm.kv.V[cur][dt * 16 + c15][0];
      s16x8 vf0 = *(const s16x8*)(vrow + (g ^ sw) * 8);
      s16x8 vf1 = *(const s16x8*)(vrow + ((g | 4) ^ sw) * 8);
      acc_o[dt] = MFMA16(vf0, pfh0, acc_o[dt]);
      acc_o[dt] = MFMA16(vf1, pfh1, acc_o[dt]);
      acc_o[dt] = MFMA16(vf0, pfl0, acc_o[dt]);
      acc_o[dt] = MFMA16(vf1, pfl1, acc_o[dt]);
    }
    __builtin_amdgcn_s_setprio(0);

    __syncthreads();   // drains gload_lds (vmcnt) -> next buffer staged; cur reads done
    cur ^= 1;
  }

  lsum += __shfl_xor(lsum, 16);
  lsum += __shfl_xor(lsum, 32);
  float inv = s_x / lsum;

  // O^T -> Ot[w][q][d] (overlay on K/V union; barrier above guarantees reads done)
  float hm = 0.0f;
  #pragma unroll
  for (int dt = 0; dt < 4; ++dt)
    #pragma unroll
    for (int r = 0; r < 4; ++r) {
      float o = acc_o[dt][r] * inv;
      hm = fmaxf(hm, fabsf(o));
      sm.Ot[w][c15][dt * 16 + 4 * g + r] = o;
    }
  int ql = l >> 2, cs = l & 3;
  #pragma unroll
  for (int j = 0; j < 4; ++j) {
    int cch = cs + 4 * j;
    float4 v = *(const float4*)&sm.Ot[w][ql][cch * 4];
    int row = qb * 64 + w * 16 + ql;
    *(float4*)&heads[((size_t)row * BATCH + b) * EMB + h * HDIM + cch * 4] = v;
  }
  blockmax_commit(hm, slots + 4);
}

extern "C" void kernel_launch(void* const* d_in, const int* in_sizes, int n_in,
                              void* d_out, int out_size, void* d_ws, size_t ws_size,
                              hipStream_t stream) {
  (void)in_sizes; (void)n_in; (void)out_size; (void)ws_size;
  const float* query = (const float*)d_in[0];
  const float* in_w  = (const float*)d_in[3];
  const float* in_b  = (const float*)d_in[4];
  const float* out_w = (const float*)d_in[5];
  const float* out_b = (const float*)d_in[6];
  float* out = (float*)d_out;

  unsigned* slots = (unsigned*)d_ws;
  char* p = (char*)d_ws + 256;
  bf16_t* q_hi   = (bf16_t*)p;                  p += (size_t)NROWS * EMB * 2;   // 8 MB
  bf16_t* q_lo   = (bf16_t*)p;                  p += (size_t)NROWS * EMB * 2;   // 8 MB
  bf16_t* Wi_int = (bf16_t*)p;                  p += (size_t)F3 * EMB * 2;      // 6 MB
  bf16_t* Wo_int = (bf16_t*)p;                  p += (size_t)EMB * EMB * 2;     // 2 MB
  float*  X_f32  = (float*)p;                   p += (size_t)NROWS * F3 * 4;    // 48 MB
  bf16_t* X_int  = (bf16_t*)p;                                                  // 24 MB
  bf16_t* Vt     = q_hi;               // q_hi dead after GEMM1; reuse (8 MB)
  bf16_t* heads_int = (bf16_t*)X_f32;  // X_f32 dead after qxv
  float*  heads_f32 = out;             // d_out doubles as heads staging

  hipMemsetAsync(d_ws, 0, 256, stream);

  dim3 b256(256);
  // weight absmax (one launch), then fused quant-weights + query split
  wabsmax_k<<<768, b256, 0, stream>>>(in_w, out_w, slots);
  prep_k<<<1024, b256, 0, stream>>>(in_w, out_w, query, Wi_int, Wo_int, q_hi, q_lo, slots);

  // GEMM1: X = (q_hi+q_lo) @ Wi_int^T * s_wi + in_b ; fused absmax(X) -> slot2
  gemm_bt_mfma_k<2><<<dim3(F3 / 128, NROWS / 128), b256, 0, stream>>>(
      q_hi, q_lo, Wi_int, in_b, X_f32, NROWS, F3, EMB, slots, -1, 0, 2);

  // merged: X Q/K cols -> int bf16 (+slot3) and V quant+transpose -> Vt
  qxv_k<<<3072, b256, 0, stream>>>(X_f32, X_int, Vt, slots);

  // attention (q requant fused) -> heads_f32 (= d_out), fused absmax(heads) -> slot4
  attn_mfma_k<<<dim3(BATCH * NH, L_SEQ / 64), b256, 0, stream>>>(X_int, Vt, heads_f32, slots);

  // heads -> int bf16
  quantf_k<<<1024, b256, 0, stream>>>(heads_f32, heads_int, NROWS * EMB / 4, slots, 4);

  // GEMM2 (64x128 tile, 512 blocks): y = heads_int @ Wo_int^T * (s_h*s_wo) + out_b
  gemm_m64_k<<<dim3(EMB / 128, NROWS / 64), b256, 0, stream>>>(
      heads_int, Wo_int, out_b, out, NROWS, EMB, EMB, slots, 4, 1, 5);

  // final fake-quant in place
  quant_k<<<1024, b256, 0, stream>>>(out, NROWS * EMB / 4, slots, 5);
}